// Round 10
// baseline (306.704 us; speedup 1.0000x reference)
//
#include <hip/hip_runtime.h>
#include <hip/hip_bf16.h>

// Embedding gather: token_ids [8,4096] int32, embedding_matrix [50257,1024] f32
// -> out [8,4096,1024] f32.  Pure memory-bound row copy.
//
// R10 (re-run of R6-R9; all hit GPU acquisition timeout):
// 16 rows per block, 2048 blocks total. 16 wave-uniform ids scalar-
// prefetched, then 16 independent 16B/lane row loads in flight
// (16 KiB/wave outstanding) before NT stores. Normal (allocating) loads on
// the embedding reads so the ~26% duplicate rows can hit L3 within an
// iteration; NT stores keep the 128 MB write-once output stream out of L3.
// If this does not move dur_us vs R4 (8 rows) and R1 (1 row), the kernel
// slice is at the HBM floor and the remainder of dur_us is fixed harness
// poison/restore traffic.

#define DIM 1024
#define F4_PER_ROW (DIM / 4)     // 256 16B-chunks per row
#define ROWS_PER_BLOCK 16

typedef float v4f __attribute__((ext_vector_type(4)));

__global__ __launch_bounds__(256) void embed_gather_kernel(
        const int* __restrict__ ids,
        const float* __restrict__ emb,
        float* __restrict__ out,
        int n_tokens) {
    const int tid  = threadIdx.x;
    const int base = blockIdx.x * ROWS_PER_BLOCK;

    const v4f* __restrict__ emb4 = reinterpret_cast<const v4f*>(emb);
    v4f* __restrict__ out4       = reinterpret_cast<v4f*>(out);

    if (base + ROWS_PER_BLOCK <= n_tokens) {
        int id[ROWS_PER_BLOCK];
#pragma unroll
        for (int r = 0; r < ROWS_PER_BLOCK; ++r)
            id[r] = ids[base + r];              // wave-uniform -> s_load (dwordx-merged)

        v4f v[ROWS_PER_BLOCK];
#pragma unroll
        for (int r = 0; r < ROWS_PER_BLOCK; ++r)
            v[r] = emb4[(size_t)id[r] * F4_PER_ROW + tid];   // 16 loads in flight

#pragma unroll
        for (int r = 0; r < ROWS_PER_BLOCK; ++r)
            __builtin_nontemporal_store(
                v[r], &out4[(size_t)(base + r) * F4_PER_ROW + tid]);
    } else {
        for (int r = 0; r < ROWS_PER_BLOCK; ++r) {
            int tok = base + r;
            if (tok >= n_tokens) break;
            int id = ids[tok];
            v4f v = emb4[(size_t)id * F4_PER_ROW + tid];
            __builtin_nontemporal_store(v, &out4[(size_t)tok * F4_PER_ROW + tid]);
        }
    }
}

extern "C" void kernel_launch(void* const* d_in, const int* in_sizes, int n_in,
                              void* d_out, int out_size, void* d_ws, size_t ws_size,
                              hipStream_t stream) {
    const int*   ids = (const int*)d_in[0];     // 8*4096 token ids
    const float* emb = (const float*)d_in[1];   // 50257*1024 embedding
    float*       out = (float*)d_out;           // 8*4096*1024

    const int n_tokens = in_sizes[0];           // 32768
    const int n_blocks = (n_tokens + ROWS_PER_BLOCK - 1) / ROWS_PER_BLOCK;
    embed_gather_kernel<<<dim3(n_blocks), dim3(256), 0, stream>>>(ids, emb, out, n_tokens);
}